// Round 5
// baseline (1952.224 us; speedup 1.0000x reference)
//
#include <hip/hip_runtime.h>

typedef unsigned short u16;
typedef unsigned int u32;
typedef unsigned long long u64;
using bfrag = __attribute__((ext_vector_type(8))) short;   // 8 bf16 (4 VGPRs)
using facc  = __attribute__((ext_vector_type(4))) float;   // MFMA accumulator

#define DEV __device__ __forceinline__
#define AGT __HIP_MEMORY_SCOPE_AGENT

// ---- workspace byte offsets ----
static constexpr size_t o_xv   = 0;          // [t*256+b][256] bf16, 6400*256
static constexpr size_t o_xt   = 3276800;
static constexpr size_t o_f0T  = 6553600;    // [256][2048] bf16
static constexpr size_t o_f1T  = 7602176;
static constexpr size_t o_UVWv = 8650752;    // [1024 p][1024 k] bf16: U|moV|W
static constexpr size_t o_UVWt = 10747904;
static constexpr size_t o_attT = 12845056;   // [2048][512] bf16
static constexpr size_t o_redT = 14942208;   // [512][1024] bf16
static constexpr size_t o_bgv  = 15990784;   // [1024] f32 gate bias (W path)
static constexpr size_t o_bgt  = 15994880;
static constexpr size_t o_mvv  = 15998976;   // [1024] f32 mob@V gate bias
static constexpr size_t o_mvt  = 16003072;
static constexpr size_t o_FW   = 16007168;   // [512][2] f32
static constexpr size_t o_fb   = 16011264;   // [2] f32
static constexpr size_t o_eh   = 16011520;   // 24 x [256][2048] bf16 (1 MB each)
static constexpr size_t o_psum = 41177344;   // 24 x [64][256] f32
static constexpr size_t o_hv   = 42750208;   // 26 x [256][256] bf16
static constexpr size_t o_ht   = 46158080;
static constexpr size_t o_rvt  = 49565952;   // 25 x [256][512] bf16
static constexpr size_t o_bar  = 56119552;   // 256 flag lines (64 B each)
static constexpr size_t o_end  = 56135936;

DEV u16 f2bf(float f) {
    u32 u = __float_as_uint(f);
    u32 r = (u + 0x7FFFu + ((u >> 16) & 1u)) >> 16;   // RNE
    return (u16)r;
}
DEV float bf2f(u16 h) { return __uint_as_float(((u32)h) << 16); }
DEV u32 pk2(float a, float b) { return (u32)f2bf(a) | ((u32)f2bf(b) << 16); }
DEV float sigm(float x) { return 1.0f / (1.0f + __expf(-x)); }
DEV float tanh2(float x) { return 2.0f * sigm(2.0f * x) - 1.0f; }  // overflow-safe tanh
DEV facc mfma16(bfrag a, bfrag b, facc c) {
    return __builtin_amdgcn_mfma_f32_16x16x32_bf16(a, b, c, 0, 0, 0);
}

// ---- grid barrier, O(1) contention:
//  arrival: release fence (wbl2 -> L3) then atomic swap to THIS block's own
//           64B flag line (no same-line RMW serialization).
//  wait:    thread tid polls flag[tid] (256 threads cover all 256 blocks)
//           with relaxed agent-scope loads (L3-direct, never stale).
//  Data visibility: writers' dirty lines pushed by the release fence; readers
//  rely on first-touch multi-buffering (no stale L2 line can exist in-run;
//  kernel-start acquire invalidates across runs).
DEV void gbar(u32* flags, int b, u32 k) {
    asm volatile("s_waitcnt vmcnt(0)" ::: "memory");   // drain this wave's stores to L2
    __syncthreads();
    if (threadIdx.x == 0) {
        __builtin_amdgcn_fence(__ATOMIC_RELEASE, "agent");  // buffer_wbl2 sc1 + wait
        (void)__hip_atomic_exchange(&flags[b * 16], k, __ATOMIC_RELAXED, AGT);
    }
    u32* myf = &flags[threadIdx.x * 16];
    while (__hip_atomic_load(myf, __ATOMIC_RELAXED, AGT) < k)
        __builtin_amdgcn_s_sleep(1);
    __syncthreads();
}

// ---------------- prep helpers (plain stores; flushed at barrier) ----------------

DEV void prep_T(const float* __restrict__ src, u16* dst, int lgK, int N, int nb, int bl, int tid) {
    int pairs = ((1 << lgK) * N) >> 1;
    int kmask = (1 << lgK) - 1;
    for (int idx = bl * 256 + tid; idx < pairs; idx += nb * 256) {
        int i = idx * 2;
        int n = i >> lgK, k = i & kmask;
        *(u32*)&dst[i] = pk2(src[(size_t)k * N + n], src[(size_t)(k + 1) * N + n]);
    }
}

// UVW[p][k]: p gate-interleaved (p=j*4+g <-> gc=g*256+j); k<256:U, 256..767: mo@V, 768..1023: W
DEV void prep_UVW(const float* U, const float* mo, const float* V, const float* W,
                  u16* dst, int nb, int bl, int tid) {
    for (int idx = bl * 256 + tid; idx < 1024 * 1024; idx += nb * 256) {
        int p = idx >> 10, k = idx & 1023;
        int j = p >> 2, g = p & 3, gc = g * 256 + j;
        float v;
        if (k < 256) v = U[(size_t)k * 1024 + gc];
        else if (k < 768) {
            int s = k - 256;
            float a = 0.f;
            for (int d = 0; d < 256; ++d) a += mo[s * 256 + d] * V[(size_t)d * 1024 + gc];
            v = a;
        } else v = W[(size_t)(k - 768) * 1024 + gc];
        dst[idx] = f2bf(v);
    }
}

DEV void prep_bias(const float* lb, const float* mob, const float* V,
                   float* bg, float* mv, int nb, int bl, int tid) {
    for (int p = bl * 256 + tid; p < 1024; p += nb * 256) {
        int j = p >> 2, g = p & 3, gc = g * 256 + j;
        bg[p] = lb[gc];
        float a = 0.f;
        for (int d = 0; d < 256; ++d) a += mob[d] * V[(size_t)d * 1024 + gc];
        mv[p] = a;
    }
}

DEV void prep_FW(const float* l0w, const float* l0b, const float* l1w, const float* l1b,
                 float* FW, float* fb, int tid) {
    for (int idx = tid; idx < 1024; idx += 256) {
        int k = idx >> 1, c = idx & 1;
        float a = 0.f;
        for (int j = 0; j < 256; ++j) a += l0w[k * 256 + j] * l1w[j * 2 + c];
        FW[idx] = a;
    }
    if (tid < 2) {
        float a = l1b[tid];
        for (int j = 0; j < 256; ++j) a += l0b[j] * l1w[j * 2 + tid];
        fb[tid] = a;
    }
}

// ---------------- args ----------------
struct KP { const float* in[26]; char* ws; float* out; };

__global__ __launch_bounds__(256) void marn_all(KP P) {
    __shared__ __align__(16) unsigned char SM[31744];
    int tid = threadIdx.x, b = blockIdx.x;
    int w = tid >> 6, l = tid & 63, lm = l & 15, kh = l >> 4;
    u32 bk = 0;
    char* ws = P.ws;

    u16* xv = (u16*)(ws + o_xv);
    u16* xt = (u16*)(ws + o_xt);
    u16* f0T = (u16*)(ws + o_f0T);
    u16* f1T = (u16*)(ws + o_f1T);
    u16* UVWv = (u16*)(ws + o_UVWv);
    u16* UVWt = (u16*)(ws + o_UVWt);
    u16* attT = (u16*)(ws + o_attT);
    u16* redT = (u16*)(ws + o_redT);
    float* bgv = (float*)(ws + o_bgv);
    float* bgt = (float*)(ws + o_bgt);
    float* mvv = (float*)(ws + o_mvv);
    float* mvt = (float*)(ws + o_mvt);
    float* FW = (float*)(ws + o_FW);
    float* fb = (float*)(ws + o_fb);
    u16* ehB = (u16*)(ws + o_eh);
    float* psB = (float*)(ws + o_psum);
    u16* hvB = (u16*)(ws + o_hv);
    u16* htB = (u16*)(ws + o_ht);
    u16* rvB = (u16*)(ws + o_rvt);
    u32* bar = (u32*)(ws + o_bar);
    const float* attb = P.in[15];
    const float* rvb = P.in[17];
    const float* rtb = P.in[19];

    // ======== stage 0: weight prep ========
    if      (b < 24)  prep_T(P.in[2], f0T, 11, 256, 24, b, tid);
    else if (b < 48)  prep_T(P.in[4], f1T, 11, 256, 24, b - 24, tid);
    else if (b < 96)  prep_T(P.in[14], attT, 9, 2048, 48, b - 48, tid);
    else if (b < 108) prep_T(P.in[16], redT, 10, 256, 12, b - 96, tid);
    else if (b < 120) prep_T(P.in[18], redT + 256 * 1024, 10, 256, 12, b - 108, tid);
    else if (b < 176) prep_UVW(P.in[7], P.in[20], P.in[8], P.in[6], UVWv, 56, b - 120, tid);
    else if (b < 232) prep_UVW(P.in[11], P.in[20], P.in[12], P.in[10], UVWt, 56, b - 176, tid);
    else if (b < 236) prep_bias(P.in[9], P.in[21], P.in[8], bgv, mvv, 4, b - 232, tid);
    else if (b < 240) prep_bias(P.in[13], P.in[21], P.in[12], bgt, mvt, 4, b - 236, tid);
    else if (b == 240) prep_FW(P.in[22], P.in[23], P.in[24], P.in[25], FW, fb, tid);
    gbar(bar, b, ++bk);

    // ======== stage 1: xv/xt = x @ fc^T + b, stored t-major [t*256+batch][256] ========
    {
        u16* Al = (u16*)SM;              // [64][72]
        u16* Bl = (u16*)(SM + 9216);     // [128][72]
        u16* Lt = (u16*)SM;              // [64][128] epilogue tile (aliases Al)
        for (int u = b; u < 400; u += 256) {
            int zs = u & 1, ny = (u >> 1) & 1, mx = u >> 2;
            const float* A = zs ? P.in[1] : P.in[0];
            const u16* BT = zs ? f1T : f0T;
            const float* bias = zs ? P.in[5] : P.in[3];
            u16* C = zs ? xt : xv;
            int m0 = mx * 64, n0 = ny * 128;
            int arow = tid >> 2, aseg = tid & 3;
            int brow = tid >> 1, bseg = tid & 1;
            facc acc[8];
#pragma unroll
            for (int i = 0; i < 8; ++i) acc[i] = (facc){0.f, 0.f, 0.f, 0.f};
            for (int c = 0; c < 32; ++c) {
                float4 av[4];
#pragma unroll
                for (int uu = 0; uu < 4; ++uu)
                    av[uu] = *(const float4*)&A[(size_t)(m0 + arow) * 2048 + c * 64 + aseg * 16 + uu * 4];
                uint4 bv[4];
#pragma unroll
                for (int uu = 0; uu < 4; ++uu)
                    bv[uu] = *(const uint4*)&BT[(size_t)(n0 + brow) * 2048 + c * 64 + bseg * 32 + uu * 8];
                __syncthreads();
                u32 pk[8];
#pragma unroll
                for (int uu = 0; uu < 4; ++uu) {
                    pk[2 * uu] = pk2(av[uu].x, av[uu].y);
                    pk[2 * uu + 1] = pk2(av[uu].z, av[uu].w);
                }
                *(uint4*)&Al[arow * 72 + aseg * 16] = make_uint4(pk[0], pk[1], pk[2], pk[3]);
                *(uint4*)&Al[arow * 72 + aseg * 16 + 8] = make_uint4(pk[4], pk[5], pk[6], pk[7]);
#pragma unroll
                for (int uu = 0; uu < 4; ++uu)
                    *(uint4*)&Bl[brow * 72 + bseg * 32 + uu * 8] = bv[uu];
                __syncthreads();
#pragma unroll
                for (int ks = 0; ks < 2; ++ks) {
                    bfrag a = *(const bfrag*)&Al[(16 * w + lm) * 72 + ks * 32 + kh * 8];
#pragma unroll
                    for (int tt = 0; tt < 8; ++tt) {
                        bfrag bb = *(const bfrag*)&Bl[(tt * 16 + lm) * 72 + ks * 32 + kh * 8];
                        acc[tt] = mfma16(a, bb, acc[tt]);
                    }
                }
            }
            __syncthreads();
#pragma unroll
            for (int tt = 0; tt < 8; ++tt)
#pragma unroll
                for (int j = 0; j < 4; ++j)
                    Lt[(16 * w + 4 * kh + j) * 128 + tt * 16 + lm] = f2bf(acc[tt][j] + bias[n0 + tt * 16 + lm]);
            __syncthreads();
            {
                int mloc = tid >> 2, seg = tid & 3;
                int mg = m0 + mloc;
                int bi = mg / 25, ti = mg - bi * 25;
                u16* drow = &C[(size_t)(ti * 256 + bi) * 256 + n0 + seg * 32];
                const uint4* lp = (const uint4*)&Lt[mloc * 128 + seg * 32];
#pragma unroll
                for (int i = 0; i < 4; ++i)
                    *(uint4*)&drow[i * 8] = lp[i];
            }
            __syncthreads();
        }
    }
    gbar(bar, b, ++bk);

    // ======== recurrence: 25 steps, 3 phases/step ========
    // P1/P2 mapping: x=b&7 (XCD under b%8 round-robin), q=b>>3; m=q&3 row-group,
    // n=8x+(q>>2): each XCD owns 8 consecutive n-slices EXCLUSIVELY -> its
    // UVW/attT slices (512K+256K) + redT (1M) stay L2-resident across steps.
    float* sscr = (float*)SM;                 // [64][33] f32
    float* ppart = (float*)(SM + 26112);      // 256 f32
    float* sinvl = (float*)(SM + 27136);      // 16 f32
    float* redscr = (float*)(SM + 27200);     // 4*16*17 f32
    float creg[2] = {0.f, 0.f};
    int xid = b & 7, q = b >> 3;

    for (int t = 0; t < 25; ++t) {
        const u16* hv_t = hvB + t * 65536;
        const u16* ht_t = htB + t * 65536;
        u16* hv_n = hvB + (t + 1) * 65536;
        u16* ht_n = htB + (t + 1) * 65536;
        const u16* rv_t = rvB + t * 131072;

        {   // ---- P1: s = [h | rvt | x] @ UVW^T + biases -> gates -> c,h ----
            int m = q & 3, n = xid * 8 + (q >> 2);
            int r0 = m * 64;
            bool sv = (n < 32);
            int p0 = (sv ? n : n - 32) * 32;     // gate-col base within modality
            const u16* UVW = sv ? UVWv : UVWt;
            const u16* hb = sv ? hv_t : ht_t;
            const u16* xb = (sv ? xv : xt) + t * 65536;
            int arow = r0 + 16 * w + lm;
            const u16* Ah = hb + arow * 256 + kh * 8;
            const u16* Ar = rv_t + arow * 512 + kh * 8;
            const u16* Ax = xb + arow * 256 + kh * 8;
            const u16* B0 = UVW + (size_t)(p0 + lm) * 1024 + kh * 8;
            const u16* B1 = UVW + (size_t)(p0 + 16 + lm) * 1024 + kh * 8;
            facc acc0 = (facc){0.f, 0.f, 0.f, 0.f}, acc1 = (facc){0.f, 0.f, 0.f, 0.f};
#pragma unroll
            for (int ks = 0; ks < 8; ++ks) {
                bfrag a = *(const bfrag*)(Ah + ks * 32);
                bfrag b0 = *(const bfrag*)(B0 + ks * 32);
                bfrag b1 = *(const bfrag*)(B1 + ks * 32);
                acc0 = mfma16(a, b0, acc0);
                acc1 = mfma16(a, b1, acc1);
            }
#pragma unroll
            for (int ks = 0; ks < 16; ++ks) {
                bfrag a = *(const bfrag*)(Ar + ks * 32);
                bfrag b0 = *(const bfrag*)(B0 + 256 + ks * 32);
                bfrag b1 = *(const bfrag*)(B1 + 256 + ks * 32);
                acc0 = mfma16(a, b0, acc0);
                acc1 = mfma16(a, b1, acc1);
            }
#pragma unroll
            for (int ks = 0; ks < 8; ++ks) {
                bfrag a = *(const bfrag*)(Ax + ks * 32);
                bfrag b0 = *(const bfrag*)(B0 + 768 + ks * 32);
                bfrag b1 = *(const bfrag*)(B1 + 768 + ks * 32);
                acc0 = mfma16(a, b0, acc0);
                acc1 = mfma16(a, b1, acc1);
            }
            __syncthreads();
#pragma unroll
            for (int j = 0; j < 4; ++j) {
                sscr[(16 * w + 4 * kh + j) * 33 + lm] = acc0[j];
                sscr[(16 * w + 4 * kh + j) * 33 + 16 + lm] = acc1[j];
            }
            __syncthreads();
            const float* bg = sv ? bgv : bgt;
            const float* mv = sv ? mvv : mvt;
            float tf = (t > 0) ? 1.0f : 0.0f;
            int r = tid >> 2, jp = tid & 3;
            float h2[2];
#pragma unroll
            for (int e = 0; e < 2; ++e) {
                int p = jp * 8 + e * 4;
                float4 b4 = *(const float4*)&bg[p0 + p];
                float4 m4 = *(const float4*)&mv[p0 + p];
                float s0 = sscr[r * 33 + p + 0] + b4.x + tf * m4.x;
                float s1 = sscr[r * 33 + p + 1] + b4.y + tf * m4.y;
                float s2 = sscr[r * 33 + p + 2] + b4.z + tf * m4.z;
                float s3 = sscr[r * 33 + p + 3] + b4.w + tf * m4.w;
                float fg = sigm(s0), ig = sigm(s1), og = sigm(s2), ch = tanh2(s3);
                float cn = fg * creg[e] + ig * ch;
                creg[e] = cn;
                h2[e] = tanh2(cn) * og;
            }
            u16* hw = sv ? hv_n : ht_n;
            *(u32*)&hw[(r0 + r) * 256 + (p0 >> 2) + jp * 2] = pk2(h2[0], h2[1]);
        }
        gbar(bar, b, ++bk);

        if (t < 24) {
            u16* eh_t = ehB + (size_t)t * 524288;
            float* ps_t = psB + t * 16384;

            {   // ---- P2: exp-logits over [h_v|h_t]@attT, row-sums, eh = e*h ----
                int m = q & 3, n = xid * 8 + (q >> 2);
                int r0 = m * 64, c0 = n * 32;
                int arow = r0 + 16 * w + lm;
                const u16* A0 = hv_n + arow * 256 + kh * 8;
                const u16* A1 = ht_n + arow * 256 + kh * 8;
                const u16* B0 = attT + (size_t)(c0 + lm) * 512 + kh * 8;
                const u16* B1 = attT + (size_t)(c0 + 16 + lm) * 512 + kh * 8;
                facc acc0 = (facc){0.f, 0.f, 0.f, 0.f}, acc1 = (facc){0.f, 0.f, 0.f, 0.f};
#pragma unroll
                for (int ks = 0; ks < 8; ++ks) {
                    bfrag a = *(const bfrag*)(A0 + ks * 32);
                    bfrag b0 = *(const bfrag*)(B0 + ks * 32);
                    bfrag b1 = *(const bfrag*)(B1 + ks * 32);
                    acc0 = mfma16(a, b0, acc0);
                    acc1 = mfma16(a, b1, acc1);
                }
#pragma unroll
                for (int ks = 0; ks < 8; ++ks) {
                    bfrag a = *(const bfrag*)(A1 + ks * 32);
                    bfrag b0 = *(const bfrag*)(B0 + 256 + ks * 32);
                    bfrag b1 = *(const bfrag*)(B1 + 256 + ks * 32);
                    acc0 = mfma16(a, b0, acc0);
                    acc1 = mfma16(a, b1, acc1);
                }
                __syncthreads();
#pragma unroll
                for (int j = 0; j < 4; ++j) {
                    sscr[(16 * w + 4 * kh + j) * 33 + lm] = acc0[j];
                    sscr[(16 * w + 4 * kh + j) * 33 + 16 + lm] = acc1[j];
                }
                __syncthreads();
                int r = tid >> 2, qq = tid & 3;
                int n15 = n & 15;
                const u16* hfs = (n15 < 8) ? hv_n : ht_n;
                int hc0 = (32 * n15) & 255;
                uint4 hfv = *(const uint4*)&hfs[(r0 + r) * 256 + hc0 + qq * 8];
                const u16* hfp = (const u16*)&hfv;
                float ps = 0.f;
                u32 pk[4];
#pragma unroll
                for (int x = 0; x < 4; ++x) {
                    float e0 = __expf(sscr[r * 33 + qq * 8 + 2 * x] + attb[c0 + qq * 8 + 2 * x]);
                    float e1 = __expf(sscr[r * 33 + qq * 8 + 2 * x + 1] + attb[c0 + qq * 8 + 2 * x + 1]);
                    ps += e0 + e1;
                    pk[x] = (u32)f2bf(e0 * bf2f(hfp[2 * x])) | ((u32)f2bf(e1 * bf2f(hfp[2 * x + 1])) << 16);
                }
                *(uint4*)&eh_t[(size_t)(r0 + r) * 2048 + c0 + qq * 8] = make_uint4(pk[0], pk[1], pk[2], pk[3]);
                ppart[r * 4 + qq] = ps;
                __syncthreads();
                if (tid < 64)
                    ps_t[n * 256 + r0 + tid] =
                        ppart[tid * 4] + ppart[tid * 4 + 1] + ppart[tid * 4 + 2] + ppart[tid * 4 + 3];
            }
            gbar(bar, b, ++bk);

            {   // ---- P3: rv|rt = relu(sinv * (eh @ redT) + bias) ----
                int m = b & 15, n = b >> 4;
                int r0 = m * 16, nc0 = n * 32;
                int half = (n < 8) ? 0 : 1;
                if (tid < 64) {
                    int r = tid >> 2, qq = tid & 3;
                    float s = 0.f;
                    for (int j2 = qq * 16; j2 < qq * 16 + 16; ++j2) s += ps_t[j2 * 256 + r0 + r];
                    ppart[r * 4 + qq] = s;
                }
                __syncthreads();
                if (tid < 16)
                    sinvl[tid] = 1.0f / (ppart[tid * 4] + ppart[tid * 4 + 1] + ppart[tid * 4 + 2] + ppart[tid * 4 + 3]);
                int tt = w & 1, kh2 = w >> 1;
                const u16* Ab = eh_t + (size_t)(r0 + lm) * 2048 + half * 256 + kh * 8;
                const u16* Bb = redT + (size_t)(nc0 + tt * 16 + lm) * 1024 + kh * 8;
                facc acc = (facc){0.f, 0.f, 0.f, 0.f};
#pragma unroll
                for (int s = 0; s < 16; ++s) {
                    int ks = kh2 * 16 + s;
                    int kk = ks * 32;
                    int j = ((kk >> 8) << 9) + (kk & 255);
                    bfrag a = *(const bfrag*)(Ab + j);
                    bfrag bb = *(const bfrag*)(Bb + kk);
                    acc = mfma16(a, bb, acc);
                }
                __syncthreads();
                if (w >= 2) {
#pragma unroll
                    for (int j = 0; j < 4; ++j)
                        redscr[tt * 272 + (4 * kh + j) * 17 + lm] = acc[j];
                }
                __syncthreads();
                if (w < 2) {
#pragma unroll
                    for (int j = 0; j < 4; ++j) {
                        float v = acc[j] + redscr[tt * 272 + (4 * kh + j) * 17 + lm];
                        int rloc = 4 * kh + j;
                        int col = nc0 + tt * 16 + lm;
                        float bs = (col < 256) ? rvb[col] : rtb[col - 256];
                        v = fmaxf(sinvl[rloc] * v + bs, 0.0f);
                        sscr[rloc * 33 + tt * 16 + lm] = v;
                    }
                }
                __syncthreads();
                if (tid < 64) {
                    int rloc = tid >> 2, cp = tid & 3;
                    u16* rw = rvB + (size_t)(t + 1) * 131072;
                    u32 q0 = pk2(sscr[rloc * 33 + cp * 8 + 0], sscr[rloc * 33 + cp * 8 + 1]);
                    u32 q1 = pk2(sscr[rloc * 33 + cp * 8 + 2], sscr[rloc * 33 + cp * 8 + 3]);
                    u32 q2 = pk2(sscr[rloc * 33 + cp * 8 + 4], sscr[rloc * 33 + cp * 8 + 5]);
                    u32 q3 = pk2(sscr[rloc * 33 + cp * 8 + 6], sscr[rloc * 33 + cp * 8 + 7]);
                    *(uint4*)&rw[(size_t)(r0 + rloc) * 512 + nc0 + cp * 8] = make_uint4(q0, q1, q2, q3);
                }
            }
            gbar(bar, b, ++bk);
        }
    }

    // ======== final: out[b] = [h_v|h_t](t=25) @ (late0@late1) + folded bias ========
    {
        const u16* hv25 = hvB + 25 * 65536;
        const u16* ht25 = htB + 25 * 65536;
        if (tid < 64) {
            float a0 = 0.f, a1 = 0.f;
            u64 hv = *(const u64*)&hv25[b * 256 + tid * 4];
            u64 ht = *(const u64*)&ht25[b * 256 + tid * 4];
#pragma unroll
            for (int i = 0; i < 4; ++i) {
                int k = tid * 4 + i;
                float h0 = bf2f((u16)(hv >> (16 * i)));
                float h1 = bf2f((u16)(ht >> (16 * i)));
                a0 += h0 * FW[k * 2] + h1 * FW[(256 + k) * 2];
                a1 += h0 * FW[k * 2 + 1] + h1 * FW[(256 + k) * 2 + 1];
            }
            ppart[tid] = a0;
            ppart[64 + tid] = a1;
        }
        __syncthreads();
        if (tid < 2) {
            float s = fb[tid];
            for (int i = 0; i < 64; ++i) s += ppart[tid * 64 + i];
            P.out[b * 2 + tid] = s;
        }
    }
}

// ---------------- host ----------------

extern "C" void kernel_launch(void* const* d_in, const int* in_sizes, int n_in,
                              void* d_out, int out_size, void* d_ws, size_t ws_size,
                              hipStream_t stream) {
    (void)in_sizes; (void)n_in; (void)out_size; (void)ws_size;
    KP P;
    for (int i = 0; i < 26; ++i) P.in[i] = (const float*)d_in[i];
    P.ws = (char*)d_ws;
    P.out = (float*)d_out;

    // zero only what is read-before-write: flags, h[0], rvt[0]
    hipMemsetAsync((char*)d_ws + o_bar, 0, o_end - o_bar, stream);
    hipMemsetAsync((char*)d_ws + o_hv, 0, 131072, stream);
    hipMemsetAsync((char*)d_ws + o_ht, 0, 131072, stream);
    hipMemsetAsync((char*)d_ws + o_rvt, 0, 262144, stream);

    void* kargs[] = { &P };
    hipError_t e = hipLaunchCooperativeKernel((void*)marn_all, dim3(256), dim3(256),
                                              kargs, 0, stream);
    if (e != hipSuccess) {
        (void)hipGetLastError();   // clear sticky error; plain launch (256 blocks co-resident)
        marn_all<<<dim3(256), dim3(256), 0, stream>>>(P);
    }
}

// Round 7
// 1727.617 us; speedup vs baseline: 1.1300x; 1.1300x over previous
//
#include <hip/hip_runtime.h>

typedef unsigned short u16;
typedef unsigned int u32;
typedef unsigned long long u64;
using bfrag = __attribute__((ext_vector_type(8))) short;   // 8 bf16 (4 VGPRs)
using facc  = __attribute__((ext_vector_type(4))) float;   // MFMA accumulator
using u32x4 = __attribute__((ext_vector_type(4))) unsigned int;  // asm-friendly 128b

#define DEV __device__ __forceinline__
#define AGT __HIP_MEMORY_SCOPE_AGENT

// ---- workspace byte offsets ----
static constexpr size_t o_xv   = 0;          // [t*256+b][256] bf16, 6400*256
static constexpr size_t o_xt   = 3276800;
static constexpr size_t o_f0T  = 6553600;    // [256][2048] bf16
static constexpr size_t o_f1T  = 7602176;
static constexpr size_t o_UVWv = 8650752;    // [1024 p][1024 k] bf16: U|moV|W
static constexpr size_t o_UVWt = 10747904;
static constexpr size_t o_attT = 12845056;   // [2048][512] bf16
static constexpr size_t o_redT = 14942208;   // [512][1024] bf16
static constexpr size_t o_bgv  = 15990784;   // [1024] f32 gate bias (W path)
static constexpr size_t o_bgt  = 15994880;
static constexpr size_t o_mvv  = 15998976;   // [1024] f32 mob@V gate bias
static constexpr size_t o_mvt  = 16003072;
static constexpr size_t o_FW   = 16007168;   // [512][2] f32
static constexpr size_t o_fb   = 16011264;   // [2] f32
static constexpr size_t o_eh   = 16011520;   // 24 x [256][2048] bf16 (1 MB each)
static constexpr size_t o_psum = 41177344;   // 24 x [64][256] f32
static constexpr size_t o_hv   = 42750208;   // 26 x [256][256] bf16
static constexpr size_t o_ht   = 46158080;
static constexpr size_t o_rvt  = 49565952;   // 25 x [256][512] bf16
static constexpr size_t o_bar  = 56119552;   // 256 flag lines (64 B each)
static constexpr size_t o_end  = 56135936;

DEV u16 f2bf(float f) {
    u32 u = __float_as_uint(f);
    u32 r = (u + 0x7FFFu + ((u >> 16) & 1u)) >> 16;   // RNE
    return (u16)r;
}
DEV float bf2f(u16 h) { return __uint_as_float(((u32)h) << 16); }
DEV u32 pk2(float a, float b) { return (u32)f2bf(a) | ((u32)f2bf(b) << 16); }
DEV float sigm(float x) { return 1.0f / (1.0f + __expf(-x)); }
DEV float tanh2(float x) { return 2.0f * sigm(2.0f * x) - 1.0f; }  // overflow-safe tanh
DEV facc mfma16(bfrag a, bfrag b, facc c) {
    return __builtin_amdgcn_mfma_f32_16x16x32_bf16(a, b, c, 0, 0, 0);
}

// ---- write-through stores (sc0 sc1: device-visible at the coherence point,
//      no dirty L2 line left behind -> barriers need no wbl2 flush) ----
DEV void stwt32(void* p, u32 v) {
    asm volatile("global_store_dword %0, %1, off sc0 sc1" :: "v"(p), "v"(v) : "memory");
}
DEV void stwt128(void* p, u32x4 v) {
    asm volatile("global_store_dwordx4 %0, %1, off sc0 sc1" :: "v"(p), "v"(v) : "memory");
}
DEV void stwtf(float* p, float v) { stwt32((void*)p, __float_as_uint(v)); }

// ---- fence-free grid barrier:
//  each wave drains its (write-through) stores, then thread 0 swaps this
//  block's own 64B flag line; wave 0 polls 4 flags/thread (L3-direct loads).
DEV void gbar(u32* flags, int b, u32 k) {
    asm volatile("s_waitcnt vmcnt(0)" ::: "memory");
    __syncthreads();
    int tid = threadIdx.x;
    if (tid == 0)
        (void)__hip_atomic_exchange(&flags[b * 16], k, __ATOMIC_RELAXED, AGT);
    if (tid < 64) {
        u32* f0 = &flags[tid * 16];
        u32* f1 = &flags[(tid + 64) * 16];
        u32* f2 = &flags[(tid + 128) * 16];
        u32* f3 = &flags[(tid + 192) * 16];
        while (__hip_atomic_load(f0, __ATOMIC_RELAXED, AGT) < k ||
               __hip_atomic_load(f1, __ATOMIC_RELAXED, AGT) < k ||
               __hip_atomic_load(f2, __ATOMIC_RELAXED, AGT) < k ||
               __hip_atomic_load(f3, __ATOMIC_RELAXED, AGT) < k)
            __builtin_amdgcn_s_sleep(1);
    }
    __syncthreads();
}

// ---- fenced variant (wbl2): used ONCE, after weight prep (plain stores) ----
DEV void gbar_fence(u32* flags, int b, u32 k) {
    asm volatile("s_waitcnt vmcnt(0)" ::: "memory");
    __syncthreads();
    int tid = threadIdx.x;
    if (tid == 0) {
        __builtin_amdgcn_fence(__ATOMIC_RELEASE, "agent");  // wbl2: push weights to L3
        (void)__hip_atomic_exchange(&flags[b * 16], k, __ATOMIC_RELAXED, AGT);
    }
    if (tid < 64) {
        u32* f0 = &flags[tid * 16];
        u32* f1 = &flags[(tid + 64) * 16];
        u32* f2 = &flags[(tid + 128) * 16];
        u32* f3 = &flags[(tid + 192) * 16];
        while (__hip_atomic_load(f0, __ATOMIC_RELAXED, AGT) < k ||
               __hip_atomic_load(f1, __ATOMIC_RELAXED, AGT) < k ||
               __hip_atomic_load(f2, __ATOMIC_RELAXED, AGT) < k ||
               __hip_atomic_load(f3, __ATOMIC_RELAXED, AGT) < k)
            __builtin_amdgcn_s_sleep(1);
    }
    __syncthreads();
}

// ---------------- prep helpers (plain stores; flushed at the fenced barrier) ----------------

DEV void prep_T(const float* __restrict__ src, u16* dst, int lgK, int N, int nb, int bl, int tid) {
    int pairs = ((1 << lgK) * N) >> 1;
    int kmask = (1 << lgK) - 1;
    for (int idx = bl * 256 + tid; idx < pairs; idx += nb * 256) {
        int i = idx * 2;
        int n = i >> lgK, k = i & kmask;
        *(u32*)&dst[i] = pk2(src[(size_t)k * N + n], src[(size_t)(k + 1) * N + n]);
    }
}

// UVW[p][k]: p gate-interleaved (p=j*4+g <-> gc=g*256+j); k<256:U, 256..767: mo@V, 768..1023: W
DEV void prep_UVW(const float* U, const float* mo, const float* V, const float* W,
                  u16* dst, int nb, int bl, int tid) {
    for (int idx = bl * 256 + tid; idx < 1024 * 1024; idx += nb * 256) {
        int p = idx >> 10, k = idx & 1023;
        int j = p >> 2, g = p & 3, gc = g * 256 + j;
        float v;
        if (k < 256) v = U[(size_t)k * 1024 + gc];
        else if (k < 768) {
            int s = k - 256;
            float a = 0.f;
            for (int d = 0; d < 256; ++d) a += mo[s * 256 + d] * V[(size_t)d * 1024 + gc];
            v = a;
        } else v = W[(size_t)(k - 768) * 1024 + gc];
        dst[idx] = f2bf(v);
    }
}

DEV void prep_bias(const float* lb, const float* mob, const float* V,
                   float* bg, float* mv, int nb, int bl, int tid) {
    for (int p = bl * 256 + tid; p < 1024; p += nb * 256) {
        int j = p >> 2, g = p & 3, gc = g * 256 + j;
        bg[p] = lb[gc];
        float a = 0.f;
        for (int d = 0; d < 256; ++d) a += mob[d] * V[(size_t)d * 1024 + gc];
        mv[p] = a;
    }
}

DEV void prep_FW(const float* l0w, const float* l0b, const float* l1w, const float* l1b,
                 float* FW, float* fb, int tid) {
    for (int idx = tid; idx < 1024; idx += 256) {
        int k = idx >> 1, c = idx & 1;
        float a = 0.f;
        for (int j = 0; j < 256; ++j) a += l0w[k * 256 + j] * l1w[j * 2 + c];
        FW[idx] = a;
    }
    if (tid < 2) {
        float a = l1b[tid];
        for (int j = 0; j < 256; ++j) a += l0b[j] * l1w[j * 2 + tid];
        fb[tid] = a;
    }
}

// ---------------- args ----------------
struct KP { const float* in[26]; char* ws; float* out; };

__global__ __launch_bounds__(256) void marn_all(KP P) {
    __shared__ __align__(16) unsigned char SM[31744];
    int tid = threadIdx.x, b = blockIdx.x;
    int w = tid >> 6, l = tid & 63, lm = l & 15, kh = l >> 4;
    u32 bk = 0;
    char* ws = P.ws;

    u16* xv = (u16*)(ws + o_xv);
    u16* xt = (u16*)(ws + o_xt);
    u16* f0T = (u16*)(ws + o_f0T);
    u16* f1T = (u16*)(ws + o_f1T);
    u16* UVWv = (u16*)(ws + o_UVWv);
    u16* UVWt = (u16*)(ws + o_UVWt);
    u16* attT = (u16*)(ws + o_attT);
    u16* redT = (u16*)(ws + o_redT);
    float* bgv = (float*)(ws + o_bgv);
    float* bgt = (float*)(ws + o_bgt);
    float* mvv = (float*)(ws + o_mvv);
    float* mvt = (float*)(ws + o_mvt);
    float* FW = (float*)(ws + o_FW);
    float* fb = (float*)(ws + o_fb);
    u16* ehB = (u16*)(ws + o_eh);
    float* psB = (float*)(ws + o_psum);
    u16* hvB = (u16*)(ws + o_hv);
    u16* htB = (u16*)(ws + o_ht);
    u16* rvB = (u16*)(ws + o_rvt);
    u32* bar = (u32*)(ws + o_bar);
    const float* attb = P.in[15];
    const float* rvb = P.in[17];
    const float* rtb = P.in[19];

    // ======== stage 0: weight prep (plain stores -> fenced barrier) ========
    if      (b < 24)  prep_T(P.in[2], f0T, 11, 256, 24, b, tid);
    else if (b < 48)  prep_T(P.in[4], f1T, 11, 256, 24, b - 24, tid);
    else if (b < 96)  prep_T(P.in[14], attT, 9, 2048, 48, b - 48, tid);
    else if (b < 108) prep_T(P.in[16], redT, 10, 256, 12, b - 96, tid);
    else if (b < 120) prep_T(P.in[18], redT + 256 * 1024, 10, 256, 12, b - 108, tid);
    else if (b < 176) prep_UVW(P.in[7], P.in[20], P.in[8], P.in[6], UVWv, 56, b - 120, tid);
    else if (b < 232) prep_UVW(P.in[11], P.in[20], P.in[12], P.in[10], UVWt, 56, b - 176, tid);
    else if (b < 236) prep_bias(P.in[9], P.in[21], P.in[8], bgv, mvv, 4, b - 232, tid);
    else if (b < 240) prep_bias(P.in[13], P.in[21], P.in[12], bgt, mvt, 4, b - 236, tid);
    else if (b == 240) prep_FW(P.in[22], P.in[23], P.in[24], P.in[25], FW, fb, tid);
    gbar_fence(bar, b, ++bk);

    // ======== stage 1: xv/xt = x @ fc^T + b (write-through outputs) ========
    {
        u16* Al = (u16*)SM;              // [64][72]
        u16* Bl = (u16*)(SM + 9216);     // [128][72]
        u16* Lt = (u16*)SM;              // [64][128] epilogue tile (aliases Al)
        for (int u = b; u < 400; u += 256) {
            int zs = u & 1, ny = (u >> 1) & 1, mx = u >> 2;
            const float* A = zs ? P.in[1] : P.in[0];
            const u16* BT = zs ? f1T : f0T;
            const float* bias = zs ? P.in[5] : P.in[3];
            u16* C = zs ? xt : xv;
            int m0 = mx * 64, n0 = ny * 128;
            int arow = tid >> 2, aseg = tid & 3;
            int brow = tid >> 1, bseg = tid & 1;
            facc acc[8];
#pragma unroll
            for (int i = 0; i < 8; ++i) acc[i] = (facc){0.f, 0.f, 0.f, 0.f};
            for (int c = 0; c < 32; ++c) {
                float4 av[4];
#pragma unroll
                for (int uu = 0; uu < 4; ++uu)
                    av[uu] = *(const float4*)&A[(size_t)(m0 + arow) * 2048 + c * 64 + aseg * 16 + uu * 4];
                uint4 bv[4];
#pragma unroll
                for (int uu = 0; uu < 4; ++uu)
                    bv[uu] = *(const uint4*)&BT[(size_t)(n0 + brow) * 2048 + c * 64 + bseg * 32 + uu * 8];
                __syncthreads();
                u32 pk[8];
#pragma unroll
                for (int uu = 0; uu < 4; ++uu) {
                    pk[2 * uu] = pk2(av[uu].x, av[uu].y);
                    pk[2 * uu + 1] = pk2(av[uu].z, av[uu].w);
                }
                *(uint4*)&Al[arow * 72 + aseg * 16] = make_uint4(pk[0], pk[1], pk[2], pk[3]);
                *(uint4*)&Al[arow * 72 + aseg * 16 + 8] = make_uint4(pk[4], pk[5], pk[6], pk[7]);
#pragma unroll
                for (int uu = 0; uu < 4; ++uu)
                    *(uint4*)&Bl[brow * 72 + bseg * 32 + uu * 8] = bv[uu];
                __syncthreads();
#pragma unroll
                for (int ks = 0; ks < 2; ++ks) {
                    bfrag a = *(const bfrag*)&Al[(16 * w + lm) * 72 + ks * 32 + kh * 8];
#pragma unroll
                    for (int tt = 0; tt < 8; ++tt) {
                        bfrag bb = *(const bfrag*)&Bl[(tt * 16 + lm) * 72 + ks * 32 + kh * 8];
                        acc[tt] = mfma16(a, bb, acc[tt]);
                    }
                }
            }
            __syncthreads();
#pragma unroll
            for (int tt = 0; tt < 8; ++tt)
#pragma unroll
                for (int j = 0; j < 4; ++j)
                    Lt[(16 * w + 4 * kh + j) * 128 + tt * 16 + lm] = f2bf(acc[tt][j] + bias[n0 + tt * 16 + lm]);
            __syncthreads();
            {
                int mloc = tid >> 2, seg = tid & 3;
                int mg = m0 + mloc;
                int bi = mg / 25, ti = mg - bi * 25;
                u16* drow = &C[(size_t)(ti * 256 + bi) * 256 + n0 + seg * 32];
                const u32x4* lp = (const u32x4*)&Lt[mloc * 128 + seg * 32];
#pragma unroll
                for (int i = 0; i < 4; ++i)
                    stwt128(&drow[i * 8], lp[i]);
            }
            __syncthreads();
        }
    }
    gbar(bar, b, ++bk);

    // ======== recurrence: 25 steps, 3 phases/step ========
    float* sscr = (float*)SM;                 // [64][33] f32
    float* ppart = (float*)(SM + 26112);      // 256 f32
    float* sinvl = (float*)(SM + 27136);      // 16 f32
    float* redscr = (float*)(SM + 27200);     // 4*16*17 f32
    float creg[2] = {0.f, 0.f};
    int xid = b & 7, q = b >> 3;

    for (int t = 0; t < 25; ++t) {
        const u16* hv_t = hvB + t * 65536;
        const u16* ht_t = htB + t * 65536;
        u16* hv_n = hvB + (t + 1) * 65536;
        u16* ht_n = htB + (t + 1) * 65536;
        const u16* rv_t = rvB + t * 131072;

        {   // ---- P1: s = [h | rvt | x] @ UVW^T + biases -> gates -> c,h ----
            int m = q & 3, n = xid * 8 + (q >> 2);
            int r0 = m * 64;
            bool sv = (n < 32);
            int p0 = (sv ? n : n - 32) * 32;     // gate-col base within modality
            const u16* UVW = sv ? UVWv : UVWt;
            const u16* hb = sv ? hv_t : ht_t;
            const u16* xb = (sv ? xv : xt) + t * 65536;
            int arow = r0 + 16 * w + lm;
            const u16* Ah = hb + arow * 256 + kh * 8;
            const u16* Ar = rv_t + arow * 512 + kh * 8;
            const u16* Ax = xb + arow * 256 + kh * 8;
            const u16* B0 = UVW + (size_t)(p0 + lm) * 1024 + kh * 8;
            const u16* B1 = UVW + (size_t)(p0 + 16 + lm) * 1024 + kh * 8;
            facc acc0 = (facc){0.f, 0.f, 0.f, 0.f}, acc1 = (facc){0.f, 0.f, 0.f, 0.f};
#pragma unroll
            for (int ks = 0; ks < 8; ++ks) {
                bfrag a = *(const bfrag*)(Ah + ks * 32);
                bfrag b0 = *(const bfrag*)(B0 + ks * 32);
                bfrag b1 = *(const bfrag*)(B1 + ks * 32);
                acc0 = mfma16(a, b0, acc0);
                acc1 = mfma16(a, b1, acc1);
            }
#pragma unroll
            for (int ks = 0; ks < 16; ++ks) {
                bfrag a = *(const bfrag*)(Ar + ks * 32);
                bfrag b0 = *(const bfrag*)(B0 + 256 + ks * 32);
                bfrag b1 = *(const bfrag*)(B1 + 256 + ks * 32);
                acc0 = mfma16(a, b0, acc0);
                acc1 = mfma16(a, b1, acc1);
            }
#pragma unroll
            for (int ks = 0; ks < 8; ++ks) {
                bfrag a = *(const bfrag*)(Ax + ks * 32);
                bfrag b0 = *(const bfrag*)(B0 + 768 + ks * 32);
                bfrag b1 = *(const bfrag*)(B1 + 768 + ks * 32);
                acc0 = mfma16(a, b0, acc0);
                acc1 = mfma16(a, b1, acc1);
            }
            __syncthreads();
#pragma unroll
            for (int j = 0; j < 4; ++j) {
                sscr[(16 * w + 4 * kh + j) * 33 + lm] = acc0[j];
                sscr[(16 * w + 4 * kh + j) * 33 + 16 + lm] = acc1[j];
            }
            __syncthreads();
            const float* bg = sv ? bgv : bgt;
            const float* mv = sv ? mvv : mvt;
            float tf = (t > 0) ? 1.0f : 0.0f;
            int r = tid >> 2, jp = tid & 3;
            float h2[2];
#pragma unroll
            for (int e = 0; e < 2; ++e) {
                int p = jp * 8 + e * 4;
                float4 b4 = *(const float4*)&bg[p0 + p];
                float4 m4 = *(const float4*)&mv[p0 + p];
                float s0 = sscr[r * 33 + p + 0] + b4.x + tf * m4.x;
                float s1 = sscr[r * 33 + p + 1] + b4.y + tf * m4.y;
                float s2 = sscr[r * 33 + p + 2] + b4.z + tf * m4.z;
                float s3 = sscr[r * 33 + p + 3] + b4.w + tf * m4.w;
                float fg = sigm(s0), ig = sigm(s1), og = sigm(s2), ch = tanh2(s3);
                float cn = fg * creg[e] + ig * ch;
                creg[e] = cn;
                h2[e] = tanh2(cn) * og;
            }
            u16* hw = sv ? hv_n : ht_n;
            stwt32(&hw[(r0 + r) * 256 + (p0 >> 2) + jp * 2], pk2(h2[0], h2[1]));
        }
        gbar(bar, b, ++bk);

        if (t < 24) {
            u16* eh_t = ehB + (size_t)t * 524288;
            float* ps_t = psB + t * 16384;

            {   // ---- P2: exp-logits over [h_v|h_t]@attT, row-sums, eh = e*h ----
                int m = q & 3, n = xid * 8 + (q >> 2);
                int r0 = m * 64, c0 = n * 32;
                int arow = r0 + 16 * w + lm;
                const u16* A0 = hv_n + arow * 256 + kh * 8;
                const u16* A1 = ht_n + arow * 256 + kh * 8;
                const u16* B0 = attT + (size_t)(c0 + lm) * 512 + kh * 8;
                const u16* B1 = attT + (size_t)(c0 + 16 + lm) * 512 + kh * 8;
                facc acc0 = (facc){0.f, 0.f, 0.f, 0.f}, acc1 = (facc){0.f, 0.f, 0.f, 0.f};
#pragma unroll
                for (int ks = 0; ks < 8; ++ks) {
                    bfrag a = *(const bfrag*)(A0 + ks * 32);
                    bfrag b0 = *(const bfrag*)(B0 + ks * 32);
                    bfrag b1 = *(const bfrag*)(B1 + ks * 32);
                    acc0 = mfma16(a, b0, acc0);
                    acc1 = mfma16(a, b1, acc1);
                }
#pragma unroll
                for (int ks = 0; ks < 8; ++ks) {
                    bfrag a = *(const bfrag*)(A1 + ks * 32);
                    bfrag b0 = *(const bfrag*)(B0 + 256 + ks * 32);
                    bfrag b1 = *(const bfrag*)(B1 + 256 + ks * 32);
                    acc0 = mfma16(a, b0, acc0);
                    acc1 = mfma16(a, b1, acc1);
                }
                __syncthreads();
#pragma unroll
                for (int j = 0; j < 4; ++j) {
                    sscr[(16 * w + 4 * kh + j) * 33 + lm] = acc0[j];
                    sscr[(16 * w + 4 * kh + j) * 33 + 16 + lm] = acc1[j];
                }
                __syncthreads();
                int r = tid >> 2, qq = tid & 3;
                int n15 = n & 15;
                const u16* hfs = (n15 < 8) ? hv_n : ht_n;
                int hc0 = (32 * n15) & 255;
                uint4 hfv = *(const uint4*)&hfs[(r0 + r) * 256 + hc0 + qq * 8];
                const u16* hfp = (const u16*)&hfv;
                float ps = 0.f;
                u32 pk[4];
#pragma unroll
                for (int x = 0; x < 4; ++x) {
                    float e0 = __expf(sscr[r * 33 + qq * 8 + 2 * x] + attb[c0 + qq * 8 + 2 * x]);
                    float e1 = __expf(sscr[r * 33 + qq * 8 + 2 * x + 1] + attb[c0 + qq * 8 + 2 * x + 1]);
                    ps += e0 + e1;
                    pk[x] = (u32)f2bf(e0 * bf2f(hfp[2 * x])) | ((u32)f2bf(e1 * bf2f(hfp[2 * x + 1])) << 16);
                }
                stwt128(&eh_t[(size_t)(r0 + r) * 2048 + c0 + qq * 8], (u32x4){pk[0], pk[1], pk[2], pk[3]});
                ppart[r * 4 + qq] = ps;
                __syncthreads();
                if (tid < 64)
                    stwtf(&ps_t[n * 256 + r0 + tid],
                          ppart[tid * 4] + ppart[tid * 4 + 1] + ppart[tid * 4 + 2] + ppart[tid * 4 + 3]);
            }
            gbar(bar, b, ++bk);

            {   // ---- P3: rv|rt = relu(sinv * (eh @ redT) + bias) ----
                int m = b & 15, n = b >> 4;
                int r0 = m * 16, nc0 = n * 32;
                int half = (n < 8) ? 0 : 1;
                if (tid < 64) {
                    int r = tid >> 2, qq = tid & 3;
                    float s = 0.f;
                    for (int j2 = qq * 16; j2 < qq * 16 + 16; ++j2) s += ps_t[j2 * 256 + r0 + r];
                    ppart[r * 4 + qq] = s;
                }
                __syncthreads();
                if (tid < 16)
                    sinvl[tid] = 1.0f / (ppart[tid * 4] + ppart[tid * 4 + 1] + ppart[tid * 4 + 2] + ppart[tid * 4 + 3]);
                int tt = w & 1, kh2 = w >> 1;
                const u16* Ab = eh_t + (size_t)(r0 + lm) * 2048 + half * 256 + kh * 8;
                const u16* Bb = redT + (size_t)(nc0 + tt * 16 + lm) * 1024 + kh * 8;
                facc acc = (facc){0.f, 0.f, 0.f, 0.f};
#pragma unroll
                for (int s = 0; s < 16; ++s) {
                    int ks = kh2 * 16 + s;
                    int kk = ks * 32;
                    int j = ((kk >> 8) << 9) + (kk & 255);
                    bfrag a = *(const bfrag*)(Ab + j);
                    bfrag bb = *(const bfrag*)(Bb + kk);
                    acc = mfma16(a, bb, acc);
                }
                __syncthreads();
                if (w >= 2) {
#pragma unroll
                    for (int j = 0; j < 4; ++j)
                        redscr[tt * 272 + (4 * kh + j) * 17 + lm] = acc[j];
                }
                __syncthreads();
                if (w < 2) {
#pragma unroll
                    for (int j = 0; j < 4; ++j) {
                        float v = acc[j] + redscr[tt * 272 + (4 * kh + j) * 17 + lm];
                        int rloc = 4 * kh + j;
                        int col = nc0 + tt * 16 + lm;
                        float bs = (col < 256) ? rvb[col] : rtb[col - 256];
                        v = fmaxf(sinvl[rloc] * v + bs, 0.0f);
                        sscr[rloc * 33 + tt * 16 + lm] = v;
                    }
                }
                __syncthreads();
                if (tid < 64) {
                    int rloc = tid >> 2, cp = tid & 3;
                    u16* rw = rvB + (size_t)(t + 1) * 131072;
                    u32 q0 = pk2(sscr[rloc * 33 + cp * 8 + 0], sscr[rloc * 33 + cp * 8 + 1]);
                    u32 q1 = pk2(sscr[rloc * 33 + cp * 8 + 2], sscr[rloc * 33 + cp * 8 + 3]);
                    u32 q2 = pk2(sscr[rloc * 33 + cp * 8 + 4], sscr[rloc * 33 + cp * 8 + 5]);
                    u32 q3 = pk2(sscr[rloc * 33 + cp * 8 + 6], sscr[rloc * 33 + cp * 8 + 7]);
                    stwt128(&rw[(size_t)(r0 + rloc) * 512 + nc0 + cp * 8], (u32x4){q0, q1, q2, q3});
                }
            }
            gbar(bar, b, ++bk);
        }
    }

    // ======== final: out[b] = [h_v|h_t](t=25) @ (late0@late1) + folded bias ========
    {
        const u16* hv25 = hvB + 25 * 65536;
        const u16* ht25 = htB + 25 * 65536;
        if (tid < 64) {
            float a0 = 0.f, a1 = 0.f;
            u64 hv = *(const u64*)&hv25[b * 256 + tid * 4];
            u64 ht = *(const u64*)&ht25[b * 256 + tid * 4];
#pragma unroll
            for (int i = 0; i < 4; ++i) {
                int k = tid * 4 + i;
                float h0 = bf2f((u16)(hv >> (16 * i)));
                float h1 = bf2f((u16)(ht >> (16 * i)));
                a0 += h0 * FW[k * 2] + h1 * FW[(256 + k) * 2];
                a1 += h0 * FW[k * 2 + 1] + h1 * FW[(256 + k) * 2 + 1];
            }
            ppart[tid] = a0;
            ppart[64 + tid] = a1;
        }
        __syncthreads();
        if (tid < 2) {
            float s = fb[tid];
            for (int i = 0; i < 64; ++i) s += ppart[tid * 64 + i];
            P.out[b * 2 + tid] = s;
        }
    }
}

// ---------------- host ----------------

extern "C" void kernel_launch(void* const* d_in, const int* in_sizes, int n_in,
                              void* d_out, int out_size, void* d_ws, size_t ws_size,
                              hipStream_t stream) {
    (void)in_sizes; (void)n_in; (void)out_size; (void)ws_size;
    KP P;
    for (int i = 0; i < 26; ++i) P.in[i] = (const float*)d_in[i];
    P.ws = (char*)d_ws;
    P.out = (float*)d_out;

    // zero only what is read-before-write: flags, h[0], rvt[0]
    (void)hipMemsetAsync((char*)d_ws + o_bar, 0, o_end - o_bar, stream);
    (void)hipMemsetAsync((char*)d_ws + o_hv, 0, 131072, stream);
    (void)hipMemsetAsync((char*)d_ws + o_ht, 0, 131072, stream);
    (void)hipMemsetAsync((char*)d_ws + o_rvt, 0, 262144, stream);

    void* kargs[] = { &P };
    hipError_t e = hipLaunchCooperativeKernel((void*)marn_all, dim3(256), dim3(256),
                                              kargs, 0, stream);
    if (e != hipSuccess) {
        (void)hipGetLastError();   // clear sticky error; plain launch (256 blocks co-resident)
        marn_all<<<dim3(256), dim3(256), 0, stream>>>(P);
    }
}